// Round 7
// baseline (440.568 us; speedup 1.0000x reference)
//
#include <hip/hip_runtime.h>

// Bidirectional LSTM, B=256, T=1024, V=6, D=64, U=64; out = last-step
// concat(h_f, h_b) @ Wd + bd, shape (B,1).
// Reductions: backward dir = ONE step from h0=0 (Wr_b dead); V=6 -> xproj is
// a 6-entry register table per lane; mask = 6-bit scalar.
// R5: quad-sliced dots + DPP butterfly, 1 barrier/step (386us).
// R6: own-gate activation via transpose-butterfly, 4 transc/step (348us).
// R7: LDS pipe = h only. (a) proj values live in 6 registers/lane, selected
//     by SCALAR token (no s_projP reads in-loop); (b) tokens via uniform
//     global s_load prefetch depth 2 (no s_tok); (c) h ds_reads issue FIRST
//     (LDS returns in-order per wave); (d) 8 FMA chains of depth 8 (was 4x16).

constexpr int kB = 256;
constexpr int kT = 1024;
constexpr int kV = 6;
constexpr int kD = 64;
constexpr int kU = 64;
constexpr int kG = 256; // 4*U gate columns

#define LOG2E 1.44269504f

template <int CTRL>
__device__ __forceinline__ float dppf(float x) {
    return __int_as_float(
        __builtin_amdgcn_mov_dpp(__float_as_int(x), CTRL, 0xF, 0xF, true));
}
constexpr int kXor1 = 0xB1; // quad_perm(1,0,3,2)
constexpr int kXor2 = 0x4E; // quad_perm(2,3,0,1)
constexpr int kBc0 = 0x00, kBc1 = 0x55, kBc2 = 0xAA, kBc3 = 0xFF;

__device__ __forceinline__ float fast_rcp(float x) { return __builtin_amdgcn_rcpf(x); }
__device__ __forceinline__ float exp2_f(float x)   { return __builtin_amdgcn_exp2f(x); }
__device__ __forceinline__ float sig_f(float z)  { return fast_rcp(1.0f + exp2_f(-LOG2E * z)); }
__device__ __forceinline__ float tanh_f(float z) { return 2.0f * fast_rcp(1.0f + exp2_f(-2.0f * LOG2E * z)) - 1.0f; }

__global__ __launch_bounds__(256, 1) void bilstm_last_kernel(
    const int*   __restrict__ tokens, // (B,T)
    const float* __restrict__ emb,    // (6,64)
    const float* __restrict__ Wk_f,   // (64,256)
    const float* __restrict__ Wr_f,   // (64,256)
    const float* __restrict__ b_f,    // (256)
    const float* __restrict__ Wk_b,   // (64,256)
    const float* __restrict__ b_b,    // (256)
    const float* __restrict__ Wd,     // (128)
    const float* __restrict__ bd,     // (1)
    float*       __restrict__ out)    // (B)
{
    __shared__ float s_emb[kV * kD];
    __shared__ float s_projP[kV * kG];            // PERMUTED xproj_f (setup only)
    __shared__ float __align__(16) s_h[2][kU];    // double-buffered hidden
    __shared__ float s_act[kG];                   // backward-step scratch

    const int b   = blockIdx.x;
    const int tid = threadIdx.x;
    const int l   = tid & 63;       // lane in wave
    const int wv  = tid >> 6;       // wave id 0..3
    const int s   = l & 3;          // h-slice AND owned gate (0..3 = i,f,g,o)
    const int k   = l >> 2;         // 0..15
    const int u   = wv * 16 + k;    // unit owned by this quad

    const int* tb = tokens + b * kT;   // wave-uniform base -> scalar loads

    // ---- stage emb ----
    for (int i = tid; i < kV * kD; i += 256) s_emb[i] = emb[i];
    if (tid < kU) { s_h[0][tid] = 0.0f; s_h[1][tid] = 0.0f; }
    __syncthreads();

    // ---- 6-bit mask, scalarized: bit v = any(emb[v][:] != 0) ----
    unsigned int mbv = 0;
#pragma unroll
    for (int v = 0; v < kV; ++v) {
        const unsigned long long bb = __ballot(s_emb[v * kD + l] != 0.0f);
        mbv |= (bb != 0ull) ? (1u << v) : 0u;
    }
    const unsigned int smb = __builtin_amdgcn_readfirstlane(mbv);

    const int tokL = __builtin_amdgcn_readfirstlane(tb[kT - 1]);

    // ---- proj table (coalesced global reads per column tid), stored PERMUTED
    // so lane q picks up proj[v][ (q&3)*64 + u(q) ] at s_projP[v*256+q].
    float a0 = b_f[tid], a1 = a0, a2 = a0, a3 = a0, a4 = a0, a5 = a0;
    float accb = b_b[tid];
    for (int d = 0; d < kD; ++d) {
        const float wkf = Wk_f[d * kG + tid];
        const float wkb = Wk_b[d * kG + tid];
        a0 = fmaf(s_emb[0 * kD + d], wkf, a0);
        a1 = fmaf(s_emb[1 * kD + d], wkf, a1);
        a2 = fmaf(s_emb[2 * kD + d], wkf, a2);
        a3 = fmaf(s_emb[3 * kD + d], wkf, a3);
        a4 = fmaf(s_emb[4 * kD + d], wkf, a4);
        a5 = fmaf(s_emb[5 * kD + d], wkf, a5);
        accb = fmaf(s_emb[tokL * kD + d], wkb, accb);
    }
    {   // inverse perm: lane q wanting column 'tid' is q = w0*64 + k0*4 + g0
        const int g0 = tid >> 6, u0 = tid & 63, w0 = u0 >> 4, k0 = u0 & 15;
        const int q = w0 * 64 + k0 * 4 + g0;
        s_projP[0 * kG + q] = a0;
        s_projP[1 * kG + q] = a1;
        s_projP[2 * kG + q] = a2;
        s_projP[3 * kG + q] = a3;
        s_projP[4 * kG + q] = a4;
        s_projP[5 * kG + q] = a5;
    }

    // ---- backward single step: z = xproj_b only (h0=0, c0=0 -> f dead) ----
    float ab;
    if (tid < 128)      ab = sig_f(accb);
    else if (tid < 192) ab = tanh_f(accb);
    else                ab = sig_f(accb);
    s_act[tid] = ab;
    __syncthreads();   // covers s_projP stores + s_act
    float hb_val = 0.0f;
    if (tid < kU) {
        const float cb = s_act[tid] * s_act[2 * kU + tid];
        const float hb = s_act[3 * kU + tid] * tanh_f(cb);
        hb_val = ((smb >> tokL) & 1) ? hb : 0.0f;
    }

    // ---- per-lane proj registers: one per vocab value (own gate column) ----
    const float pr0 = s_projP[0 * kG + tid];
    const float pr1 = s_projP[1 * kG + tid];
    const float pr2 = s_projP[2 * kG + tid];
    const float pr3 = s_projP[3 * kG + tid];
    const float pr4 = s_projP[4 * kG + tid];
    const float pr5 = s_projP[5 * kG + tid];

    // ---- recurrent weights: 16 named float4 (unified VGPR/AGPR file) ----
#define DECLW(g, jb)                                                  \
    float4 wq##g##_##jb;                                              \
    wq##g##_##jb.x = Wr_f[(16 * s + 4 * jb + 0) * kG + (g * 64 + u)]; \
    wq##g##_##jb.y = Wr_f[(16 * s + 4 * jb + 1) * kG + (g * 64 + u)]; \
    wq##g##_##jb.z = Wr_f[(16 * s + 4 * jb + 2) * kG + (g * 64 + u)]; \
    wq##g##_##jb.w = Wr_f[(16 * s + 4 * jb + 3) * kG + (g * 64 + u)];
    DECLW(0,0) DECLW(0,1) DECLW(0,2) DECLW(0,3)
    DECLW(1,0) DECLW(1,1) DECLW(1,2) DECLW(1,3)
    DECLW(2,0) DECLW(2,1) DECLW(2,2) DECLW(2,3)
    DECLW(3,0) DECLW(3,1) DECLW(3,2) DECLW(3,3)
#undef DECLW

    // per-lane activation constants: gate s==2 is tanh, others sigmoid
    const bool  isg    = (s == 2);
    const float aScale = isg ? -2.0f * LOG2E : -LOG2E;
    const float aMul   = isg ? 2.0f : 1.0f;
    const float aAdd   = isg ? -1.0f : 0.0f;

    float c = 0.0f, hreg = 0.0f;
    __syncthreads();   // s_h init + pr reads complete before loop

    // ---- scalar token pipeline, depth 2 (SMEM, off the LDS pipe) ----
    int stok0 = __builtin_amdgcn_readfirstlane(tb[0]);
    int stok1 = __builtin_amdgcn_readfirstlane(tb[1]);

#define MACQ(g, jb, ch)                                    \
        p##g##ch = fmaf(hv##jb.x, wq##g##_##jb.x, p##g##ch); \
        p##g##ch = fmaf(hv##jb.y, wq##g##_##jb.y, p##g##ch); \
        p##g##ch = fmaf(hv##jb.z, wq##g##_##jb.z, p##g##ch); \
        p##g##ch = fmaf(hv##jb.w, wq##g##_##jb.w, p##g##ch);

#define STEP(RP, WP, TT)                                                      \
    {                                                                         \
        /* h reads FIRST: nothing ahead of them in the in-order LDS queue */  \
        const float4* hp = (const float4*)s_h[RP];                            \
        const float4 hv0 = hp[s * 4 + 0];                                     \
        const float4 hv1 = hp[s * 4 + 1];                                     \
        const float4 hv2 = hp[s * 4 + 2];                                     \
        const float4 hv3 = hp[s * 4 + 3];                                     \
        /* scalar-prefetch token t+2 (SMEM) */                                \
        const int stok2 = __builtin_amdgcn_readfirstlane(                     \
            tb[((TT) + 2) & (kT - 1)]);                                       \
        /* own-gate proj select by scalar token (off critical path) */        \
        const float zp = stok0 == 0 ? pr0 : stok0 == 1 ? pr1 :                \
                         stok0 == 2 ? pr2 : stok0 == 3 ? pr3 :                \
                         stok0 == 4 ? pr4 : pr5;                              \
        const int mskc = (int)((smb >> stok0) & 1);                           \
        float p0a = 0.f, p1a = 0.f, p2a = 0.f, p3a = 0.f;                     \
        float p0b = 0.f, p1b = 0.f, p2b = 0.f, p3b = 0.f;                     \
        MACQ(0,0,a) MACQ(1,0,a) MACQ(2,0,a) MACQ(3,0,a)                       \
        MACQ(0,1,a) MACQ(1,1,a) MACQ(2,1,a) MACQ(3,1,a)                       \
        MACQ(0,2,b) MACQ(1,2,b) MACQ(2,2,b) MACQ(3,2,b)                       \
        MACQ(0,3,b) MACQ(1,3,b) MACQ(2,3,b) MACQ(3,3,b)                       \
        float p0 = p0a + p0b, p1 = p1a + p1b;                                 \
        float p2 = p2a + p2b, p3 = p3a + p3b;                                 \
        p0 += dppf<kXor1>(p0); p1 += dppf<kXor1>(p1);                         \
        p2 += dppf<kXor1>(p2); p3 += dppf<kXor1>(p3);                         \
        float X = (s & 1) ? p1 : p0;                                          \
        float Y = (s & 1) ? p3 : p2;                                          \
        X += dppf<kXor2>(X); Y += dppf<kXor2>(Y);                             \
        const float z = ((s & 2) ? Y : X) + zp;                               \
        const float e = exp2_f(z * aScale);                                   \
        const float r = fast_rcp(1.0f + e);                                   \
        const float a = fmaf(r, aMul, aAdd);                                  \
        const float ai = dppf<kBc0>(a);                                       \
        const float af = dppf<kBc1>(a);                                       \
        const float ag = dppf<kBc2>(a);                                       \
        const float ao = dppf<kBc3>(a);                                       \
        const float cn = fmaf(af, c, ai * ag);                                \
        const float hn = ao * tanh_f(cn);                                     \
        if (mskc) { c = cn; hreg = hn; }   /* uniform branch */               \
        if (s == 0) s_h[WP][u] = hreg;                                        \
        __syncthreads();                                                      \
        stok0 = stok1; stok1 = stok2;                                         \
    }

    for (int t = 0; t < kT; t += 2) {
        STEP(0, 1, t)
        STEP(1, 0, t + 1)
    }
#undef STEP
#undef MACQ

    // final h in s_h[0] (step 1023 reads s_h[1], writes s_h[0])
    if (tid < kU) {
        float v = s_h[0][tid] * Wd[tid] + hb_val * Wd[kU + tid];
#pragma unroll
        for (int off = 32; off > 0; off >>= 1) v += __shfl_down(v, off, 64);
        if (tid == 0) out[b] = v + bd[0];
    }
}

extern "C" void kernel_launch(void* const* d_in, const int* in_sizes, int n_in,
                              void* d_out, int out_size, void* d_ws, size_t ws_size,
                              hipStream_t stream) {
    const int*   tokens = (const int*)d_in[0];
    const float* emb    = (const float*)d_in[1];
    const float* Wk_f   = (const float*)d_in[2];
    const float* Wr_f   = (const float*)d_in[3];
    const float* b_f    = (const float*)d_in[4];
    const float* Wk_b   = (const float*)d_in[5];
    // d_in[6] = Wr_b: unused (backward runs one step from h0=0)
    const float* b_b    = (const float*)d_in[7];
    const float* Wd     = (const float*)d_in[8];
    const float* bd     = (const float*)d_in[9];
    float* out = (float*)d_out;

    bilstm_last_kernel<<<kB, 256, 0, stream>>>(
        tokens, emb, Wk_f, Wr_f, b_f, Wk_b, b_b, Wd, bd, out);
}

// Round 8
// 350.260 us; speedup vs baseline: 1.2578x; 1.2578x over previous
//
#include <hip/hip_runtime.h>

// Bidirectional LSTM, B=256, T=1024, V=6, D=64, U=64; out = last-step
// concat(h_f, h_b) @ Wd + bd, shape (B,1).
// Reductions: backward dir = ONE step from h0=0 (Wr_b dead); V=6 -> xproj is
// a 6x256 table; mask = 6-bit scalar.
// R5: quad-sliced dots + DPP butterfly, 1 barrier/step (386us).
// R6: own-gate activation via transpose-butterfly, scalar token pipeline
//     through LDS, 4 transcendentals/step (348us). BEST so far.
// R7: SMEM per-step token loads -> REGRESSION (394us, FETCH +0.5MB, the
//     s_load latency lands in the pre-barrier lgkmcnt drain). Reverted.
// R8: R6 +(a) h ds_reads issue FIRST (LDS returns in-order per wave; tok/proj
//     b32 reads no longer delay the h data) +(b) 64 MACs as 32 v_pk_fma_f32
//     via ext_vector_type(2) + __builtin_elementwise_fma (FMA issue 128->64).

constexpr int kB = 256;
constexpr int kT = 1024;
constexpr int kV = 6;
constexpr int kD = 64;
constexpr int kU = 64;
constexpr int kG = 256; // 4*U gate columns

#define LOG2E 1.44269504f

typedef float v2f __attribute__((ext_vector_type(2)));

template <int CTRL>
__device__ __forceinline__ float dppf(float x) {
    return __int_as_float(
        __builtin_amdgcn_mov_dpp(__float_as_int(x), CTRL, 0xF, 0xF, true));
}
constexpr int kXor1 = 0xB1; // quad_perm(1,0,3,2)
constexpr int kXor2 = 0x4E; // quad_perm(2,3,0,1)
constexpr int kBc0 = 0x00, kBc1 = 0x55, kBc2 = 0xAA, kBc3 = 0xFF;

__device__ __forceinline__ float fast_rcp(float x) { return __builtin_amdgcn_rcpf(x); }
__device__ __forceinline__ float exp2_f(float x)   { return __builtin_amdgcn_exp2f(x); }
__device__ __forceinline__ float sig_f(float z)  { return fast_rcp(1.0f + exp2_f(-LOG2E * z)); }
__device__ __forceinline__ float tanh_f(float z) { return 2.0f * fast_rcp(1.0f + exp2_f(-2.0f * LOG2E * z)) - 1.0f; }

__global__ __launch_bounds__(256, 1) void bilstm_last_kernel(
    const int*   __restrict__ tokens, // (B,T)
    const float* __restrict__ emb,    // (6,64)
    const float* __restrict__ Wk_f,   // (64,256)
    const float* __restrict__ Wr_f,   // (64,256)
    const float* __restrict__ b_f,    // (256)
    const float* __restrict__ Wk_b,   // (64,256)
    const float* __restrict__ b_b,    // (256)
    const float* __restrict__ Wd,     // (128)
    const float* __restrict__ bd,     // (1)
    float*       __restrict__ out)    // (B)
{
    __shared__ float s_emb[kV * kD];
    __shared__ float s_projP[kV * kG];            // PERMUTED xproj_f table
    __shared__ int   s_tok[kT];
    __shared__ float __align__(16) s_h[2][kU];    // double-buffered hidden
    __shared__ float s_act[kG];                   // backward-step scratch

    const int b   = blockIdx.x;
    const int tid = threadIdx.x;
    const int l   = tid & 63;       // lane in wave
    const int wv  = tid >> 6;       // wave id 0..3
    const int s   = l & 3;          // h-slice AND owned gate (0..3 = i,f,g,o)
    const int k   = l >> 2;         // 0..15
    const int u   = wv * 16 + k;    // unit owned by this quad

    // ---- stage emb + tokens ----
    for (int i = tid; i < kV * kD; i += 256) s_emb[i] = emb[i];
    ((int4*)s_tok)[tid] = ((const int4*)(tokens + b * kT))[tid];
    if (tid < kU) { s_h[0][tid] = 0.0f; s_h[1][tid] = 0.0f; }
    __syncthreads();

    // ---- 6-bit mask, scalarized: bit v = any(emb[v][:] != 0) ----
    unsigned int mbv = 0;
#pragma unroll
    for (int v = 0; v < kV; ++v) {
        const unsigned long long bb = __ballot(s_emb[v * kD + l] != 0.0f);
        mbv |= (bb != 0ull) ? (1u << v) : 0u;
    }
    const unsigned int smb = __builtin_amdgcn_readfirstlane(mbv);

    const int tokL = s_tok[kT - 1];

    // ---- proj table (coalesced global reads per column tid), stored PERMUTED
    // so lane q of the step loop reads proj[v][ (q&3)*64 + u(q) ] at
    // s_projP[v*256+q].
    float a0 = b_f[tid], a1 = a0, a2 = a0, a3 = a0, a4 = a0, a5 = a0;
    float accb = b_b[tid];
    for (int d = 0; d < kD; ++d) {
        const float wkf = Wk_f[d * kG + tid];
        const float wkb = Wk_b[d * kG + tid];
        a0 = fmaf(s_emb[0 * kD + d], wkf, a0);
        a1 = fmaf(s_emb[1 * kD + d], wkf, a1);
        a2 = fmaf(s_emb[2 * kD + d], wkf, a2);
        a3 = fmaf(s_emb[3 * kD + d], wkf, a3);
        a4 = fmaf(s_emb[4 * kD + d], wkf, a4);
        a5 = fmaf(s_emb[5 * kD + d], wkf, a5);
        accb = fmaf(s_emb[tokL * kD + d], wkb, accb);
    }
    {   // inverse perm: lane q wanting column 'tid' is q = w0*64 + k0*4 + g0
        const int g0 = tid >> 6, u0 = tid & 63, w0 = u0 >> 4, k0 = u0 & 15;
        const int q = w0 * 64 + k0 * 4 + g0;
        s_projP[0 * kG + q] = a0;
        s_projP[1 * kG + q] = a1;
        s_projP[2 * kG + q] = a2;
        s_projP[3 * kG + q] = a3;
        s_projP[4 * kG + q] = a4;
        s_projP[5 * kG + q] = a5;
    }

    // ---- backward single step: z = xproj_b only (h0=0, c0=0 -> f dead) ----
    float ab;
    if (tid < 128)      ab = sig_f(accb);
    else if (tid < 192) ab = tanh_f(accb);
    else                ab = sig_f(accb);
    s_act[tid] = ab;
    __syncthreads();
    float hb_val = 0.0f;
    if (tid < kU) {
        const float cb = s_act[tid] * s_act[2 * kU + tid];
        const float hb = s_act[3 * kU + tid] * tanh_f(cb);
        hb_val = ((smb >> tokL) & 1) ? hb : 0.0f;
    }

    // ---- recurrent weights: 16 named float4 (unified VGPR/AGPR file) ----
#define DECLW(g, jb)                                                  \
    float4 wq##g##_##jb;                                              \
    wq##g##_##jb.x = Wr_f[(16 * s + 4 * jb + 0) * kG + (g * 64 + u)]; \
    wq##g##_##jb.y = Wr_f[(16 * s + 4 * jb + 1) * kG + (g * 64 + u)]; \
    wq##g##_##jb.z = Wr_f[(16 * s + 4 * jb + 2) * kG + (g * 64 + u)]; \
    wq##g##_##jb.w = Wr_f[(16 * s + 4 * jb + 3) * kG + (g * 64 + u)];
    DECLW(0,0) DECLW(0,1) DECLW(0,2) DECLW(0,3)
    DECLW(1,0) DECLW(1,1) DECLW(1,2) DECLW(1,3)
    DECLW(2,0) DECLW(2,1) DECLW(2,2) DECLW(2,3)
    DECLW(3,0) DECLW(3,1) DECLW(3,2) DECLW(3,3)
#undef DECLW

    // per-lane activation constants: gate s==2 is tanh, others sigmoid
    const bool  isg    = (s == 2);
    const float aScale = isg ? -2.0f * LOG2E : -LOG2E;
    const float aMul   = isg ? 2.0f : 1.0f;
    const float aAdd   = isg ? -1.0f : 0.0f;

    float c = 0.0f, hreg = 0.0f;
    __syncthreads();   // projP + s_h init visible

    // ---- scalar token pipeline, depth 2 (through LDS, as in R6) ----
    int stok0 = __builtin_amdgcn_readfirstlane(s_tok[0]);
    float zcur = s_projP[stok0 * kG + tid];   // own-gate proj for this lane
    int   mskc = (smb >> stok0) & 1;          // scalar
    int   stokA = __builtin_amdgcn_readfirstlane(s_tok[1]);

    // 64 MACs as packed-fp32: 2 v2f chains per gate, depth 4 each
#define MACQ(g, jb)                                                       \
        pk##g = __builtin_elementwise_fma(                                \
            (v2f){hv##jb.x, hv##jb.y},                                    \
            (v2f){wq##g##_##jb.x, wq##g##_##jb.y}, pk##g);                \
        qk##g = __builtin_elementwise_fma(                                \
            (v2f){hv##jb.z, hv##jb.w},                                    \
            (v2f){wq##g##_##jb.z, wq##g##_##jb.w}, qk##g);

#define STEP(RP, WP, TT)                                                      \
    {                                                                         \
        /* h reads FIRST: nothing ahead of them in the in-order LDS queue */  \
        const float4* hp = (const float4*)s_h[RP];                            \
        const float4 hv0 = hp[s * 4 + 0];                                     \
        const float4 hv1 = hp[s * 4 + 1];                                     \
        const float4 hv2 = hp[s * 4 + 2];                                     \
        const float4 hv3 = hp[s * 4 + 3];                                     \
        /* prefetches behind h in the queue; consumed next step / at rotate */\
        const int   vtokB = s_tok[((TT) + 2) & (kT - 1)];                     \
        const float znext = s_projP[stokA * kG + tid];                        \
        const int   mskn  = (int)((smb >> stokA) & 1);                        \
        v2f pk0 = {0.f,0.f}, pk1 = {0.f,0.f}, pk2 = {0.f,0.f}, pk3 = {0.f,0.f};\
        v2f qk0 = {0.f,0.f}, qk1 = {0.f,0.f}, qk2 = {0.f,0.f}, qk3 = {0.f,0.f};\
        MACQ(0,0) MACQ(1,0) MACQ(2,0) MACQ(3,0)                               \
        MACQ(0,1) MACQ(1,1) MACQ(2,1) MACQ(3,1)                               \
        MACQ(0,2) MACQ(1,2) MACQ(2,2) MACQ(3,2)                               \
        MACQ(0,3) MACQ(1,3) MACQ(2,3) MACQ(3,3)                               \
        const v2f v0 = pk0 + qk0, v1 = pk1 + qk1;                             \
        const v2f v2 = pk2 + qk2, v3 = pk3 + qk3;                             \
        float p0 = v0.x + v0.y, p1 = v1.x + v1.y;                             \
        float p2 = v2.x + v2.y, p3 = v3.x + v3.y;                             \
        /* round 1: 2-lane sums over xor1 pairs, all gates */                 \
        p0 += dppf<kXor1>(p0); p1 += dppf<kXor1>(p1);                         \
        p2 += dppf<kXor1>(p2); p3 += dppf<kXor1>(p3);                         \
        /* select own pair-gate (xor2 partner has same s&1 -> gate-uniform) */\
        float X = (s & 1) ? p1 : p0;                                          \
        float Y = (s & 1) ? p3 : p2;                                          \
        X += dppf<kXor2>(X); Y += dppf<kXor2>(Y);                             \
        const float z = ((s & 2) ? Y : X) + zcur;                             \
        /* one activation per lane (own gate) */                              \
        const float e = exp2_f(z * aScale);                                   \
        const float r = fast_rcp(1.0f + e);                                   \
        const float a = fmaf(r, aMul, aAdd);                                  \
        /* quad broadcasts: gate q lives in lane q of the quad */             \
        const float ai = dppf<kBc0>(a);                                       \
        const float af = dppf<kBc1>(a);                                       \
        const float ag = dppf<kBc2>(a);                                       \
        const float ao = dppf<kBc3>(a);                                       \
        const float cn = fmaf(af, c, ai * ag);                                \
        const float hn = ao * tanh_f(cn);                                     \
        if (mskc) { c = cn; hreg = hn; }   /* uniform branch */               \
        if (s == 0) s_h[WP][u] = hreg;                                        \
        __syncthreads();                                                      \
        zcur = znext; mskc = mskn;                                            \
        stokA = __builtin_amdgcn_readfirstlane(vtokB);                        \
    }

    for (int t = 0; t < kT; t += 2) {
        STEP(0, 1, t)
        STEP(1, 0, t + 1)
    }
#undef STEP
#undef MACQ

    // final h in s_h[0] (step 1023 reads s_h[1], writes s_h[0])
    if (tid < kU) {
        float v = s_h[0][tid] * Wd[tid] + hb_val * Wd[kU + tid];
#pragma unroll
        for (int off = 32; off > 0; off >>= 1) v += __shfl_down(v, off, 64);
        if (tid == 0) out[b] = v + bd[0];
    }
}

extern "C" void kernel_launch(void* const* d_in, const int* in_sizes, int n_in,
                              void* d_out, int out_size, void* d_ws, size_t ws_size,
                              hipStream_t stream) {
    const int*   tokens = (const int*)d_in[0];
    const float* emb    = (const float*)d_in[1];
    const float* Wk_f   = (const float*)d_in[2];
    const float* Wr_f   = (const float*)d_in[3];
    const float* b_f    = (const float*)d_in[4];
    const float* Wk_b   = (const float*)d_in[5];
    // d_in[6] = Wr_b: unused (backward runs one step from h0=0)
    const float* b_b    = (const float*)d_in[7];
    const float* Wd     = (const float*)d_in[8];
    const float* bd     = (const float*)d_in[9];
    float* out = (float*)d_out;

    bilstm_last_kernel<<<kB, 256, 0, stream>>>(
        tokens, emb, Wk_f, Wr_f, b_f, Wk_b, b_b, Wd, bd, out);
}